// Round 5
// baseline (823.756 us; speedup 1.0000x reference)
//
#include <hip/hip_runtime.h>
#include <math.h>

#define B    16
#define N    20000
#define E    640000
#define NREG 2000
#define DIN  128
#define F    32
#define NEG  0.2f
#define BF   (B * F)          // 512 floats per node row; 256 uints in bf16
#define NCHUNK 8
#define CS   2500             // nodes per chunk (2500*1KB = 2.44 MB slice)
#define NBKT (NCHUNK * NREG)  // 16000 buckets

typedef unsigned int uint;

__device__ inline uint bf16pair(float a, float b) {
    uint ua = __float_as_uint(a); ua = (ua + 0x7fffu + ((ua >> 16) & 1u)) >> 16;
    uint ub = __float_as_uint(b); ub = (ub + 0x7fffu + ((ub >> 16) & 1u)) >> 16;
    return ua | (ub << 16);
}
__device__ inline float bf16lo(uint v) { return __uint_as_float(v << 16); }
__device__ inline float bf16hi(uint v) { return __uint_as_float(v & 0xffff0000u); }

// ---------------- dst histogram (random atomics) ----------------
__global__ void k_hist(const int* __restrict__ dst, int* __restrict__ counts) {
    int e = blockIdx.x * blockDim.x + threadIdx.x;
    int stride = gridDim.x * blockDim.x;
    for (; e < E; e += stride)
        atomicAdd(&counts[dst[e]], 1);
}

// ---------------- single-block exclusive scan (n <= 16384) ----------------
__global__ void k_scan(const int* __restrict__ in, int* __restrict__ out, int n) {
    __shared__ int sh[1024];
    int t = threadIdx.x;
    int chunk = (n + 1023) / 1024;
    int lo = t * chunk;
    int hi = lo + chunk; if (hi > n) hi = n;
    int local = 0;
    for (int i = lo; i < hi; ++i) local += in[i];
    sh[t] = local;
    __syncthreads();
    for (int d = 1; d < 1024; d <<= 1) {
        int v = (t >= d) ? sh[t - d] : 0;
        __syncthreads();
        sh[t] += v;
        __syncthreads();
    }
    int run = (t == 0) ? 0 : sh[t - 1];
    for (int i = lo; i < hi; ++i) { out[i] = run; run += in[i]; }
    if (t == 1023) out[n] = sh[1023];
}

// ---------------- scatter edges into CSR-by-dst ----------------
__global__ void k_scatter(const int* __restrict__ src, const int* __restrict__ dst,
                          const int* __restrict__ off, int* __restrict__ cursor,
                          int* __restrict__ csr_src, int* __restrict__ pos_of_e) {
    int e = blockIdx.x * blockDim.x + threadIdx.x;
    int stride = gridDim.x * blockDim.x;
    for (; e < E; e += stride) {
        int d = dst[e];
        int pos = off[d] + atomicAdd(&cursor[d], 1);
        csr_src[pos] = src[e];
        pos_of_e[e] = pos;
    }
}

// ---------------- bucket count for chunked pooling ----------------
// span-per-thread so wave lanes hit distinct (chunk, regulon) keys
#define BCTHREADS 4096
__global__ void k_bcount(const int* __restrict__ esrc, const int* __restrict__ edst,
                         int* __restrict__ bcount) {
    int tid = blockIdx.x * blockDim.x + threadIdx.x;
    int span = (E + BCTHREADS - 1) / BCTHREADS;
    int lo = tid * span;
    int hi = lo + span; if (hi > E) hi = E;
    for (int e = lo; e < hi; ++e) {
        int key = (edst[e] / CS) * NREG + esrc[e];
        atomicAdd(&bcount[key], 1);
    }
}

__global__ void k_bscatter(const int* __restrict__ esrc, const int* __restrict__ edst,
                           const int* __restrict__ boff, int* __restrict__ cursor2,
                           int* __restrict__ pe_dst) {
    int tid = blockIdx.x * blockDim.x + threadIdx.x;
    int span = (E + BCTHREADS - 1) / BCTHREADS;
    int lo = tid * span;
    int hi = lo + span; if (hi > E) hi = E;
    for (int e = lo; e < hi; ++e) {
        int d = edst[e];
        int key = (d / CS) * NREG + esrc[e];
        int pos = boff[key] + atomicAdd(&cursor2[key], 1);
        pe_dst[pos] = d;
    }
}

// ---------------- per-batch mean of edge_attr ----------------
#define MEAN_BLOCKS_PER_B 64
__global__ void k_mean(const float* __restrict__ eattr, float* __restrict__ meanb) {
    int b   = blockIdx.x / MEAN_BLOCKS_PER_B;
    int blk = blockIdx.x % MEAN_BLOCKS_PER_B;
    int per = (E + MEAN_BLOCKS_PER_B - 1) / MEAN_BLOCKS_PER_B;
    int lo = blk * per;
    int hi = lo + per; if (hi > E) hi = E;
    float s = 0.f;
    for (int i = lo + threadIdx.x; i < hi; i += blockDim.x)
        s += eattr[(size_t)b * E + i];
    __shared__ float sh[256];
    sh[threadIdx.x] = s;
    __syncthreads();
    for (int d = 128; d > 0; d >>= 1) {
        if (threadIdx.x < d) sh[threadIdx.x] += sh[threadIdx.x + d];
        __syncthreads();
    }
    if (threadIdx.x == 0) atomicAdd(&meanb[b], sh[0]);
}

// ---------------- scalar c_edge = dot(lin_edge, att_edge) ----------------
__global__ void k_cedge(const float* __restrict__ lin_edge,
                        const float* __restrict__ att_edge, float* __restrict__ c) {
    if (threadIdx.x == 0) {
        float s = 0.f;
        for (int f = 0; f < F; ++f) s += lin_edge[f] * att_edge[f];
        *c = s;
    }
}

// ---------------- fused: eattr tile -> alpha -> exp -> wbuf[csr_pos][B] ----------------
__global__ __launch_bounds__(256) void k_edgew(const float* __restrict__ eattr,
                                               const int* __restrict__ esrc,
                                               const int* __restrict__ edst,
                                               const int* __restrict__ pos_of_e,
                                               const float* __restrict__ a_src,
                                               const float* __restrict__ a_dst,
                                               const float* __restrict__ cedge,
                                               float* __restrict__ wbuf) {
    __shared__ float tile[B][257];
    __shared__ int ssrc[256], sdst[256], spos[256];
    int e0 = blockIdx.x * 256;
    int t = threadIdx.x;
    #pragma unroll
    for (int b = 0; b < B; ++b)
        tile[b][t] = eattr[(size_t)b * E + e0 + t];
    ssrc[t] = esrc[e0 + t];
    sdst[t] = edst[e0 + t];
    spos[t] = pos_of_e[e0 + t];
    __syncthreads();
    float c = *cedge;
    #pragma unroll
    for (int p = 0; p < 16; ++p) {
        int idx = p * 256 + t;
        int el = idx >> 4;
        int bb = idx & 15;
        float a = a_src[(size_t)ssrc[el] * B + bb]
                + a_dst[(size_t)sdst[el] * B + bb]
                + tile[bb][el] * c;
        a = a > 0.f ? a : NEG * a;
        wbuf[(size_t)spos[el] * B + bb] = __expf(a);
    }
}

// ---------------- h = x @ W -> bf16 [n][B][F]; fused a_src/a_dst ----------------
#define XS_LD 260
__global__ __launch_bounds__(256) void k_gemm(const float* __restrict__ x,
                                              const float* __restrict__ W,
                                              const float* __restrict__ att_src,
                                              const float* __restrict__ att_dst,
                                              uint* __restrict__ hu,
                                              float* __restrict__ a_src,
                                              float* __restrict__ a_dst) {
    __shared__ float Ws[DIN * F];
    __shared__ float xs[32 * XS_LD];
    int t = threadIdx.x;
    int row0 = blockIdx.x * 256;      // flattened b*N + n
    #pragma unroll
    for (int j = 0; j < 4; ++j) {
        int idx = (t + 256 * j) * 4;
        *(float4*)&Ws[idx] = *(const float4*)&W[idx];
    }
    const int lr = t & 63;
    const int fg = t >> 6;            // wave-uniform
    float acc[4][8];
    #pragma unroll
    for (int i = 0; i < 4; ++i)
        #pragma unroll
        for (int j = 0; j < 8; ++j) acc[i][j] = 0.f;

    for (int kc = 0; kc < 4; ++kc) {
        __syncthreads();
        #pragma unroll
        for (int j = 0; j < 8; ++j) {
            int p = t + 256 * j;
            int row = p >> 3;
            int kk  = (p & 7) * 4;
            float4 g = *(const float4*)&x[(size_t)(row0 + row) * DIN + kc * 32 + kk];
            xs[(kk + 0) * XS_LD + row] = g.x;
            xs[(kk + 1) * XS_LD + row] = g.y;
            xs[(kk + 2) * XS_LD + row] = g.z;
            xs[(kk + 3) * XS_LD + row] = g.w;
        }
        __syncthreads();
        #pragma unroll
        for (int k = 0; k < 32; ++k) {
            float4 xv = *(float4*)&xs[k * XS_LD + 4 * lr];
            float4 w0 = *(float4*)&Ws[(kc * 32 + k) * F + fg * 8];
            float4 w1 = *(float4*)&Ws[(kc * 32 + k) * F + fg * 8 + 4];
            float xr[4] = {xv.x, xv.y, xv.z, xv.w};
            float wr[8] = {w0.x, w0.y, w0.z, w0.w, w1.x, w1.y, w1.z, w1.w};
            #pragma unroll
            for (int i = 0; i < 4; ++i)
                #pragma unroll
                for (int j = 0; j < 8; ++j)
                    acc[i][j] = fmaf(xr[i], wr[j], acc[i][j]);
        }
    }
    #pragma unroll
    for (int i = 0; i < 4; ++i) {
        int row = row0 + lr * 4 + i;
        int b = row / N;
        int n = row - b * N;
        uint4 o;
        o.x = bf16pair(acc[i][0], acc[i][1]);
        o.y = bf16pair(acc[i][2], acc[i][3]);
        o.z = bf16pair(acc[i][4], acc[i][5]);
        o.w = bf16pair(acc[i][6], acc[i][7]);
        *(uint4*)&hu[(size_t)n * 256 + b * 16 + fg * 4] = o;
    }
    float* red = xs;
    __syncthreads();
    #pragma unroll
    for (int i = 0; i < 4; ++i) {
        float s1 = 0.f, s2 = 0.f;
        #pragma unroll
        for (int j = 0; j < 8; ++j) {
            float as = att_src[fg * 8 + j];
            float ad = att_dst[fg * 8 + j];
            s1 = fmaf(acc[i][j], as, s1);
            s2 = fmaf(acc[i][j], ad, s2);
        }
        red[fg * 256 + lr * 4 + i]        = s1;
        red[1024 + fg * 256 + lr * 4 + i] = s2;
    }
    __syncthreads();
    {
        float s1 = red[t] + red[256 + t] + red[512 + t] + red[768 + t];
        float s2 = red[1024 + t] + red[1280 + t] + red[1536 + t] + red[1792 + t];
        int row = row0 + t;
        int b = row / N;
        int n = row - b * N;
        a_src[(size_t)n * B + b] = s1;
        a_dst[(size_t)n * B + b] = s2;
    }
}

// ---------------- rep: weighted aggregate, 4-deep pipelined gather ----------------
__global__ __launch_bounds__(256) void k_rep(
    const uint* __restrict__ hu, const float* __restrict__ a_src,
    const float* __restrict__ a_dst, const float* __restrict__ wbuf,
    const float* __restrict__ bias, const float* __restrict__ meanb,
    const float* __restrict__ cedge, const int* __restrict__ dst_off,
    const int* __restrict__ csr_src, uint* __restrict__ repu) {
    int i = blockIdx.x;
    int t = threadIdx.x;
    int b  = t >> 4;
    int fp = t & 15;
    float c = *cedge;
    float meanv = meanb[b] * (1.f / (float)E);
    float al = a_src[(size_t)i * B + b] + a_dst[(size_t)i * B + b] + meanv * c;
    al = al > 0.f ? al : NEG * al;
    float s = __expf(al);
    uint hv = hu[(size_t)i * 256 + t];
    float acc0 = s * bf16lo(hv);
    float acc1 = s * bf16hi(hv);
    int lo = dst_off[i], hi = dst_off[i + 1];
    int j = lo;
    for (; j + 4 <= hi; j += 4) {
        int s0 = csr_src[j], s1 = csr_src[j+1], s2 = csr_src[j+2], s3 = csr_src[j+3];
        float w0 = wbuf[(size_t)(j+0) * B + b];
        float w1 = wbuf[(size_t)(j+1) * B + b];
        float w2 = wbuf[(size_t)(j+2) * B + b];
        float w3 = wbuf[(size_t)(j+3) * B + b];
        uint v0 = hu[(size_t)s0 * 256 + t];
        uint v1 = hu[(size_t)s1 * 256 + t];
        uint v2 = hu[(size_t)s2 * 256 + t];
        uint v3 = hu[(size_t)s3 * 256 + t];
        s += w0 + w1 + w2 + w3;
        acc0 = fmaf(w0, bf16lo(v0), acc0);
        acc1 = fmaf(w0, bf16hi(v0), acc1);
        acc0 = fmaf(w1, bf16lo(v1), acc0);
        acc1 = fmaf(w1, bf16hi(v1), acc1);
        acc0 = fmaf(w2, bf16lo(v2), acc0);
        acc1 = fmaf(w2, bf16hi(v2), acc1);
        acc0 = fmaf(w3, bf16lo(v3), acc0);
        acc1 = fmaf(w3, bf16hi(v3), acc1);
    }
    for (; j < hi; ++j) {
        int sj = csr_src[j];
        float wv = wbuf[(size_t)j * B + b];
        uint v = hu[(size_t)sj * 256 + t];
        s += wv;
        acc0 = fmaf(wv, bf16lo(v), acc0);
        acc1 = fmaf(wv, bf16hi(v), acc1);
    }
    float inv = 1.f / s;
    repu[(size_t)i * 256 + t] = bf16pair(acc0 * inv + bias[2 * fp],
                                         acc1 * inv + bias[2 * fp + 1]);
}

// ---------------- chunked pooling: block = (chunk, regulon), 8-deep pipeline ----------------
__global__ __launch_bounds__(256) void k_pool(const uint* __restrict__ repu,
                                              const int* __restrict__ boff,
                                              const int* __restrict__ pe_dst,
                                              float* __restrict__ partial) {
    int key = blockIdx.x;            // c * NREG + r (chunk-major dispatch)
    int c = key / NREG;
    int r = key - c * NREG;
    int t = threadIdx.x;
    int lo = boff[key], hi = boff[key + 1];
    float acc0 = 0.f, acc1 = 0.f;
    int e = lo;
    for (; e + 8 <= hi; e += 8) {
        int d0 = pe_dst[e+0], d1 = pe_dst[e+1], d2 = pe_dst[e+2], d3 = pe_dst[e+3];
        int d4 = pe_dst[e+4], d5 = pe_dst[e+5], d6 = pe_dst[e+6], d7 = pe_dst[e+7];
        uint v0 = repu[(size_t)d0 * 256 + t];
        uint v1 = repu[(size_t)d1 * 256 + t];
        uint v2 = repu[(size_t)d2 * 256 + t];
        uint v3 = repu[(size_t)d3 * 256 + t];
        uint v4 = repu[(size_t)d4 * 256 + t];
        uint v5 = repu[(size_t)d5 * 256 + t];
        uint v6 = repu[(size_t)d6 * 256 + t];
        uint v7 = repu[(size_t)d7 * 256 + t];
        acc0 += (bf16lo(v0) + bf16lo(v1)) + (bf16lo(v2) + bf16lo(v3))
              + (bf16lo(v4) + bf16lo(v5)) + (bf16lo(v6) + bf16lo(v7));
        acc1 += (bf16hi(v0) + bf16hi(v1)) + (bf16hi(v2) + bf16hi(v3))
              + (bf16hi(v4) + bf16hi(v5)) + (bf16hi(v6) + bf16hi(v7));
    }
    for (; e < hi; ++e) {
        int d = pe_dst[e];
        uint v = repu[(size_t)d * 256 + t];
        acc0 += bf16lo(v);
        acc1 += bf16hi(v);
    }
    float2 o = {acc0, acc1};
    *(float2*)&partial[((size_t)r * NCHUNK + c) * BF + 2 * t] = o;
}

__global__ __launch_bounds__(256) void k_combine(const uint* __restrict__ repu,
                                                 const float* __restrict__ partial,
                                                 float* __restrict__ out) {
    int r = blockIdx.x;
    int t = threadIdx.x;
    int b  = t >> 4;
    int fp = t & 15;
    uint v = repu[(size_t)r * 256 + t];      // self term
    float s0 = bf16lo(v), s1 = bf16hi(v);
    #pragma unroll
    for (int c = 0; c < NCHUNK; ++c) {
        float2 p = *(const float2*)&partial[((size_t)r * NCHUNK + c) * BF + 2 * t];
        s0 += p.x; s1 += p.y;
    }
    float2 o = {s0, s1};
    *(float2*)&out[(size_t)b * NREG * F + r * F + 2 * fp] = o;
}

extern "C" void kernel_launch(void* const* d_in, const int* in_sizes, int n_in,
                              void* d_out, int out_size, void* d_ws, size_t ws_size,
                              hipStream_t stream) {
    const float* x        = (const float*)d_in[0];
    const float* eattr    = (const float*)d_in[1];
    const float* W        = (const float*)d_in[2];
    const float* att_src  = (const float*)d_in[3];
    const float* att_dst  = (const float*)d_in[4];
    const float* lin_edge = (const float*)d_in[5];
    const float* att_edge = (const float*)d_in[6];
    const float* bias     = (const float*)d_in[7];
    const int*   esrc     = (const int*)d_in[8];
    const int*   edst     = (const int*)d_in[9];
    float* out = (float*)d_out;

    char* ws = (char*)d_ws;
    size_t off = 0;
    auto alloc = [&](size_t bytes) -> void* {
        void* p = ws + off;
        off = (off + bytes + 255) & ~(size_t)255;
        return p;
    };
    uint*  hu    = (uint*)alloc((size_t)N * 256 * 4);          // 20.5 MB bf16 h
    uint*  repu  = (uint*)alloc((size_t)N * 256 * 4);          // 20.5 MB bf16 rep
    float* wbuf  = (float*)alloc((size_t)E * B * 4);           // 41 MB [csr_pos][B]
    float* a_src = (float*)alloc((size_t)N * B * 4);
    float* a_dst = (float*)alloc((size_t)N * B * 4);
    int* dst_off = (int*)alloc((size_t)(N + 1) * 4);
    int* csr_src = (int*)alloc((size_t)E * 4);
    int* pos_of_e= (int*)alloc((size_t)E * 4);
    int* pe_dst  = (int*)alloc((size_t)E * 4);
    int* boff    = (int*)alloc((size_t)(NBKT + 1) * 4);
    char* zbase   = ws + off;
    int* counts   = (int*)alloc((size_t)N * 4);
    int* cursor   = (int*)alloc((size_t)N * 4);
    int* bcount   = (int*)alloc((size_t)NBKT * 4);
    int* cursor2  = (int*)alloc((size_t)NBKT * 4);
    float* meanb  = (float*)alloc((size_t)B * 4);
    float* cedge  = (float*)alloc(4);
    size_t zbytes = (size_t)((ws + off) - zbase);
    float* partial = wbuf;   // alias: wbuf dead after k_rep; 32.8 MB <= 41 MB

    hipMemsetAsync(zbase, 0, zbytes, stream);

    k_hist<<<1024, 256, 0, stream>>>(edst, counts);
    k_scan<<<1, 1024, 0, stream>>>(counts, dst_off, N);
    k_scatter<<<1024, 256, 0, stream>>>(esrc, edst, dst_off, cursor,
                                        csr_src, pos_of_e);
    k_bcount<<<BCTHREADS / 256, 256, 0, stream>>>(esrc, edst, bcount);
    k_scan<<<1, 1024, 0, stream>>>(bcount, boff, NBKT);
    k_bscatter<<<BCTHREADS / 256, 256, 0, stream>>>(esrc, edst, boff, cursor2, pe_dst);
    k_mean<<<B * MEAN_BLOCKS_PER_B, 256, 0, stream>>>(eattr, meanb);
    k_cedge<<<1, 64, 0, stream>>>(lin_edge, att_edge, cedge);
    k_gemm<<<(B * N) / 256, 256, 0, stream>>>(x, W, att_src, att_dst,
                                              hu, a_src, a_dst);
    k_edgew<<<E / 256, 256, 0, stream>>>(eattr, esrc, edst, pos_of_e,
                                         a_src, a_dst, cedge, wbuf);
    k_rep<<<N, 256, 0, stream>>>(hu, a_src, a_dst, wbuf, bias, meanb, cedge,
                                 dst_off, csr_src, repu);
    k_pool<<<NBKT, 256, 0, stream>>>(repu, boff, pe_dst, partial);
    k_combine<<<NREG, 256, 0, stream>>>(repu, partial, out);
}

// Round 6
// 556.140 us; speedup vs baseline: 1.4812x; 1.4812x over previous
//
#include <hip/hip_runtime.h>
#include <math.h>

#define B    16
#define N    20000
#define E    640000
#define NREG 2000
#define DIN  128
#define F    32
#define NEG  0.2f
#define BF   (B * F)          // 512 floats per node row; 256 uints in bf16
#define NCHUNK 8
#define CS   2500             // nodes per chunk (2500*1KB = 2.44 MB repu slice)

typedef unsigned int uint;

__device__ inline uint bf16pair(float a, float b) {
    uint ua = __float_as_uint(a); ua = (ua + 0x7fffu + ((ua >> 16) & 1u)) >> 16;
    uint ub = __float_as_uint(b); ub = (ub + 0x7fffu + ((ub >> 16) & 1u)) >> 16;
    return ua | (ub << 16);
}
__device__ inline float bf16lo(uint v) { return __uint_as_float(v << 16); }
__device__ inline float bf16hi(uint v) { return __uint_as_float(v & 0xffff0000u); }

// ---------------- dst histogram (random atomics) ----------------
__global__ void k_hist(const int* __restrict__ dst, int* __restrict__ counts) {
    int e = blockIdx.x * blockDim.x + threadIdx.x;
    int stride = gridDim.x * blockDim.x;
    for (; e < E; e += stride)
        atomicAdd(&counts[dst[e]], 1);
}

// ---------------- regulon offsets via binary search (esrc sorted) ----------------
__global__ void k_roff(const int* __restrict__ esrc, int* __restrict__ roff) {
    int r = blockIdx.x * blockDim.x + threadIdx.x;
    if (r > NREG) return;
    int lo = 0, hi = E;
    while (lo < hi) {
        int mid = (lo + hi) >> 1;
        if (esrc[mid] < r) lo = mid + 1; else hi = mid;
    }
    roff[r] = lo;
}

// ---------------- single-block exclusive scan ----------------
__global__ void k_scan(const int* __restrict__ in, int* __restrict__ out, int n) {
    __shared__ int sh[1024];
    int t = threadIdx.x;
    int chunk = (n + 1023) / 1024;
    int lo = t * chunk;
    int hi = lo + chunk; if (hi > n) hi = n;
    int local = 0;
    for (int i = lo; i < hi; ++i) local += in[i];
    sh[t] = local;
    __syncthreads();
    for (int d = 1; d < 1024; d <<= 1) {
        int v = (t >= d) ? sh[t - d] : 0;
        __syncthreads();
        sh[t] += v;
        __syncthreads();
    }
    int run = (t == 0) ? 0 : sh[t - 1];
    for (int i = lo; i < hi; ++i) { out[i] = run; run += in[i]; }
    if (t == 1023) out[n] = sh[1023];
}

// ---------------- scatter edges into CSR-by-dst ----------------
__global__ void k_scatter(const int* __restrict__ src, const int* __restrict__ dst,
                          const int* __restrict__ off, int* __restrict__ cursor,
                          int* __restrict__ csr_src, int* __restrict__ pos_of_e) {
    int e = blockIdx.x * blockDim.x + threadIdx.x;
    int stride = gridDim.x * blockDim.x;
    for (; e < E; e += stride) {
        int d = dst[e];
        int pos = off[d] + atomicAdd(&cursor[d], 1);
        csr_src[pos] = src[e];
        pos_of_e[e] = pos;
    }
}

// ---------------- per-regulon chunk bucketing (LDS only, no global atomics) ----------------
// edges of regulon r are contiguous [roff[r], roff[r+1]) since esrc is sorted
__global__ __launch_bounds__(256) void k_bucket(const int* __restrict__ edst,
                                                const int* __restrict__ roff,
                                                int* __restrict__ boff,
                                                int* __restrict__ pe_dst) {
    __shared__ int cnt[NCHUNK], pref[NCHUNK], cur[NCHUNK];
    int r = blockIdx.x;
    int t = threadIdx.x;
    int lo = roff[r], hi = roff[r + 1];
    if (t < NCHUNK) { cnt[t] = 0; cur[t] = 0; }
    __syncthreads();
    for (int e = lo + t; e < hi; e += 256)
        atomicAdd(&cnt[edst[e] / CS], 1);
    __syncthreads();
    if (t == 0) {
        int run = 0;
        #pragma unroll
        for (int c = 0; c < NCHUNK; ++c) { pref[c] = run; run += cnt[c]; }
    }
    __syncthreads();
    if (t < NCHUNK) boff[r * NCHUNK + t] = lo + pref[t];
    if (r == 0 && t == 0) boff[NREG * NCHUNK] = E;
    for (int e = lo + t; e < hi; e += 256) {
        int d = edst[e];
        int c = d / CS;
        int pos = lo + pref[c] + atomicAdd(&cur[c], 1);
        pe_dst[pos] = d;
    }
}

// ---------------- per-batch mean of edge_attr ----------------
#define MEAN_BLOCKS_PER_B 64
__global__ void k_mean(const float* __restrict__ eattr, float* __restrict__ meanb) {
    int b   = blockIdx.x / MEAN_BLOCKS_PER_B;
    int blk = blockIdx.x % MEAN_BLOCKS_PER_B;
    int per = (E + MEAN_BLOCKS_PER_B - 1) / MEAN_BLOCKS_PER_B;
    int lo = blk * per;
    int hi = lo + per; if (hi > E) hi = E;
    float s = 0.f;
    for (int i = lo + threadIdx.x; i < hi; i += blockDim.x)
        s += eattr[(size_t)b * E + i];
    __shared__ float sh[256];
    sh[threadIdx.x] = s;
    __syncthreads();
    for (int d = 128; d > 0; d >>= 1) {
        if (threadIdx.x < d) sh[threadIdx.x] += sh[threadIdx.x + d];
        __syncthreads();
    }
    if (threadIdx.x == 0) atomicAdd(&meanb[b], sh[0]);
}

// ---------------- scalar c_edge = dot(lin_edge, att_edge) ----------------
__global__ void k_cedge(const float* __restrict__ lin_edge,
                        const float* __restrict__ att_edge, float* __restrict__ c) {
    if (threadIdx.x == 0) {
        float s = 0.f;
        for (int f = 0; f < F; ++f) s += lin_edge[f] * att_edge[f];
        *c = s;
    }
}

// ---------------- fused: eattr tile -> alpha -> exp -> wbuf[csr_pos][B] ----------------
__global__ __launch_bounds__(256) void k_edgew(const float* __restrict__ eattr,
                                               const int* __restrict__ esrc,
                                               const int* __restrict__ edst,
                                               const int* __restrict__ pos_of_e,
                                               const float* __restrict__ a_src,
                                               const float* __restrict__ a_dst,
                                               const float* __restrict__ cedge,
                                               float* __restrict__ wbuf) {
    __shared__ float tile[B][257];
    __shared__ int ssrc[256], sdst[256], spos[256];
    int e0 = blockIdx.x * 256;
    int t = threadIdx.x;
    #pragma unroll
    for (int b = 0; b < B; ++b)
        tile[b][t] = eattr[(size_t)b * E + e0 + t];
    ssrc[t] = esrc[e0 + t];
    sdst[t] = edst[e0 + t];
    spos[t] = pos_of_e[e0 + t];
    __syncthreads();
    float c = *cedge;
    #pragma unroll
    for (int p = 0; p < 16; ++p) {
        int idx = p * 256 + t;
        int el = idx >> 4;
        int bb = idx & 15;
        float a = a_src[(size_t)ssrc[el] * B + bb]
                + a_dst[(size_t)sdst[el] * B + bb]
                + tile[bb][el] * c;
        a = a > 0.f ? a : NEG * a;
        wbuf[(size_t)spos[el] * B + bb] = __expf(a);
    }
}

// ---------------- h = x @ W -> bf16 [n][B][F]; fused a_src/a_dst ----------------
#define XS_LD 260
__global__ __launch_bounds__(256) void k_gemm(const float* __restrict__ x,
                                              const float* __restrict__ W,
                                              const float* __restrict__ att_src,
                                              const float* __restrict__ att_dst,
                                              uint* __restrict__ hu,
                                              float* __restrict__ a_src,
                                              float* __restrict__ a_dst) {
    __shared__ float Ws[DIN * F];
    __shared__ float xs[32 * XS_LD];
    int t = threadIdx.x;
    int row0 = blockIdx.x * 256;      // flattened b*N + n
    #pragma unroll
    for (int j = 0; j < 4; ++j) {
        int idx = (t + 256 * j) * 4;
        *(float4*)&Ws[idx] = *(const float4*)&W[idx];
    }
    const int lr = t & 63;
    const int fg = t >> 6;            // wave-uniform
    float acc[4][8];
    #pragma unroll
    for (int i = 0; i < 4; ++i)
        #pragma unroll
        for (int j = 0; j < 8; ++j) acc[i][j] = 0.f;

    for (int kc = 0; kc < 4; ++kc) {
        __syncthreads();
        #pragma unroll
        for (int j = 0; j < 8; ++j) {
            int p = t + 256 * j;
            int row = p >> 3;
            int kk  = (p & 7) * 4;
            float4 g = *(const float4*)&x[(size_t)(row0 + row) * DIN + kc * 32 + kk];
            xs[(kk + 0) * XS_LD + row] = g.x;
            xs[(kk + 1) * XS_LD + row] = g.y;
            xs[(kk + 2) * XS_LD + row] = g.z;
            xs[(kk + 3) * XS_LD + row] = g.w;
        }
        __syncthreads();
        #pragma unroll
        for (int k = 0; k < 32; ++k) {
            float4 xv = *(float4*)&xs[k * XS_LD + 4 * lr];
            float4 w0 = *(float4*)&Ws[(kc * 32 + k) * F + fg * 8];
            float4 w1 = *(float4*)&Ws[(kc * 32 + k) * F + fg * 8 + 4];
            float xr[4] = {xv.x, xv.y, xv.z, xv.w};
            float wr[8] = {w0.x, w0.y, w0.z, w0.w, w1.x, w1.y, w1.z, w1.w};
            #pragma unroll
            for (int i = 0; i < 4; ++i)
                #pragma unroll
                for (int j = 0; j < 8; ++j)
                    acc[i][j] = fmaf(xr[i], wr[j], acc[i][j]);
        }
    }
    #pragma unroll
    for (int i = 0; i < 4; ++i) {
        int row = row0 + lr * 4 + i;
        int b = row / N;
        int n = row - b * N;
        uint4 o;
        o.x = bf16pair(acc[i][0], acc[i][1]);
        o.y = bf16pair(acc[i][2], acc[i][3]);
        o.z = bf16pair(acc[i][4], acc[i][5]);
        o.w = bf16pair(acc[i][6], acc[i][7]);
        *(uint4*)&hu[(size_t)n * 256 + b * 16 + fg * 4] = o;
    }
    float* red = xs;
    __syncthreads();
    #pragma unroll
    for (int i = 0; i < 4; ++i) {
        float s1 = 0.f, s2 = 0.f;
        #pragma unroll
        for (int j = 0; j < 8; ++j) {
            float as = att_src[fg * 8 + j];
            float ad = att_dst[fg * 8 + j];
            s1 = fmaf(acc[i][j], as, s1);
            s2 = fmaf(acc[i][j], ad, s2);
        }
        red[fg * 256 + lr * 4 + i]        = s1;
        red[1024 + fg * 256 + lr * 4 + i] = s2;
    }
    __syncthreads();
    {
        float s1 = red[t] + red[256 + t] + red[512 + t] + red[768 + t];
        float s2 = red[1024 + t] + red[1280 + t] + red[1536 + t] + red[1792 + t];
        int row = row0 + t;
        int b = row / N;
        int n = row - b * N;
        a_src[(size_t)n * B + b] = s1;
        a_dst[(size_t)n * B + b] = s2;
    }
}

// ---------------- rep: weighted aggregate, 4-deep pipelined gather ----------------
__global__ __launch_bounds__(256) void k_rep(
    const uint* __restrict__ hu, const float* __restrict__ a_src,
    const float* __restrict__ a_dst, const float* __restrict__ wbuf,
    const float* __restrict__ bias, const float* __restrict__ meanb,
    const float* __restrict__ cedge, const int* __restrict__ dst_off,
    const int* __restrict__ csr_src, uint* __restrict__ repu) {
    int i = blockIdx.x;
    int t = threadIdx.x;
    int b  = t >> 4;
    int fp = t & 15;
    float c = *cedge;
    float meanv = meanb[b] * (1.f / (float)E);
    float al = a_src[(size_t)i * B + b] + a_dst[(size_t)i * B + b] + meanv * c;
    al = al > 0.f ? al : NEG * al;
    float s = __expf(al);
    uint hv = hu[(size_t)i * 256 + t];
    float acc0 = s * bf16lo(hv);
    float acc1 = s * bf16hi(hv);
    int lo = dst_off[i], hi = dst_off[i + 1];
    int j = lo;
    for (; j + 4 <= hi; j += 4) {
        int s0 = csr_src[j], s1 = csr_src[j+1], s2 = csr_src[j+2], s3 = csr_src[j+3];
        float w0 = wbuf[(size_t)(j+0) * B + b];
        float w1 = wbuf[(size_t)(j+1) * B + b];
        float w2 = wbuf[(size_t)(j+2) * B + b];
        float w3 = wbuf[(size_t)(j+3) * B + b];
        uint v0 = hu[(size_t)s0 * 256 + t];
        uint v1 = hu[(size_t)s1 * 256 + t];
        uint v2 = hu[(size_t)s2 * 256 + t];
        uint v3 = hu[(size_t)s3 * 256 + t];
        s += w0 + w1 + w2 + w3;
        acc0 = fmaf(w0, bf16lo(v0), acc0);
        acc1 = fmaf(w0, bf16hi(v0), acc1);
        acc0 = fmaf(w1, bf16lo(v1), acc0);
        acc1 = fmaf(w1, bf16hi(v1), acc1);
        acc0 = fmaf(w2, bf16lo(v2), acc0);
        acc1 = fmaf(w2, bf16hi(v2), acc1);
        acc0 = fmaf(w3, bf16lo(v3), acc0);
        acc1 = fmaf(w3, bf16hi(v3), acc1);
    }
    for (; j < hi; ++j) {
        int sj = csr_src[j];
        float wv = wbuf[(size_t)j * B + b];
        uint v = hu[(size_t)sj * 256 + t];
        s += wv;
        acc0 = fmaf(wv, bf16lo(v), acc0);
        acc1 = fmaf(wv, bf16hi(v), acc1);
    }
    float inv = 1.f / s;
    repu[(size_t)i * 256 + t] = bf16pair(acc0 * inv + bias[2 * fp],
                                         acc1 * inv + bias[2 * fp + 1]);
}

// ---------------- chunked pooling: block = (chunk, regulon), 8-deep pipeline ----------------
__global__ __launch_bounds__(256) void k_pool(const uint* __restrict__ repu,
                                              const int* __restrict__ boff,
                                              const int* __restrict__ pe_dst,
                                              float* __restrict__ partial) {
    int key = blockIdx.x;            // c * NREG + r (chunk-major dispatch)
    int c = key / NREG;
    int r = key - c * NREG;
    int idx = r * NCHUNK + c;        // boff is regulon-major
    int t = threadIdx.x;
    int lo = boff[idx], hi = boff[idx + 1];
    float acc0 = 0.f, acc1 = 0.f;
    int e = lo;
    for (; e + 8 <= hi; e += 8) {
        int d0 = pe_dst[e+0], d1 = pe_dst[e+1], d2 = pe_dst[e+2], d3 = pe_dst[e+3];
        int d4 = pe_dst[e+4], d5 = pe_dst[e+5], d6 = pe_dst[e+6], d7 = pe_dst[e+7];
        uint v0 = repu[(size_t)d0 * 256 + t];
        uint v1 = repu[(size_t)d1 * 256 + t];
        uint v2 = repu[(size_t)d2 * 256 + t];
        uint v3 = repu[(size_t)d3 * 256 + t];
        uint v4 = repu[(size_t)d4 * 256 + t];
        uint v5 = repu[(size_t)d5 * 256 + t];
        uint v6 = repu[(size_t)d6 * 256 + t];
        uint v7 = repu[(size_t)d7 * 256 + t];
        acc0 += (bf16lo(v0) + bf16lo(v1)) + (bf16lo(v2) + bf16lo(v3))
              + (bf16lo(v4) + bf16lo(v5)) + (bf16lo(v6) + bf16lo(v7));
        acc1 += (bf16hi(v0) + bf16hi(v1)) + (bf16hi(v2) + bf16hi(v3))
              + (bf16hi(v4) + bf16hi(v5)) + (bf16hi(v6) + bf16hi(v7));
    }
    for (; e < hi; ++e) {
        int d = pe_dst[e];
        uint v = repu[(size_t)d * 256 + t];
        acc0 += bf16lo(v);
        acc1 += bf16hi(v);
    }
    float2 o = {acc0, acc1};
    *(float2*)&partial[((size_t)r * NCHUNK + c) * BF + 2 * t] = o;
}

__global__ __launch_bounds__(256) void k_combine(const uint* __restrict__ repu,
                                                 const float* __restrict__ partial,
                                                 float* __restrict__ out) {
    int r = blockIdx.x;
    int t = threadIdx.x;
    int b  = t >> 4;
    int fp = t & 15;
    uint v = repu[(size_t)r * 256 + t];      // self term
    float s0 = bf16lo(v), s1 = bf16hi(v);
    #pragma unroll
    for (int c = 0; c < NCHUNK; ++c) {
        float2 p = *(const float2*)&partial[((size_t)r * NCHUNK + c) * BF + 2 * t];
        s0 += p.x; s1 += p.y;
    }
    float2 o = {s0, s1};
    *(float2*)&out[(size_t)b * NREG * F + r * F + 2 * fp] = o;
}

extern "C" void kernel_launch(void* const* d_in, const int* in_sizes, int n_in,
                              void* d_out, int out_size, void* d_ws, size_t ws_size,
                              hipStream_t stream) {
    const float* x        = (const float*)d_in[0];
    const float* eattr    = (const float*)d_in[1];
    const float* W        = (const float*)d_in[2];
    const float* att_src  = (const float*)d_in[3];
    const float* att_dst  = (const float*)d_in[4];
    const float* lin_edge = (const float*)d_in[5];
    const float* att_edge = (const float*)d_in[6];
    const float* bias     = (const float*)d_in[7];
    const int*   esrc     = (const int*)d_in[8];
    const int*   edst     = (const int*)d_in[9];
    float* out = (float*)d_out;

    char* ws = (char*)d_ws;
    size_t off = 0;
    auto alloc = [&](size_t bytes) -> void* {
        void* p = ws + off;
        off = (off + bytes + 255) & ~(size_t)255;
        return p;
    };
    uint*  hu    = (uint*)alloc((size_t)N * 256 * 4);          // 20.5 MB bf16 h
    uint*  repu  = (uint*)alloc((size_t)N * 256 * 4);          // 20.5 MB bf16 rep
    float* wbuf  = (float*)alloc((size_t)E * B * 4);           // 41 MB [csr_pos][B]
    float* a_src = (float*)alloc((size_t)N * B * 4);
    float* a_dst = (float*)alloc((size_t)N * B * 4);
    int* dst_off = (int*)alloc((size_t)(N + 1) * 4);
    int* roff    = (int*)alloc((size_t)(NREG + 1) * 4);
    int* csr_src = (int*)alloc((size_t)E * 4);
    int* pos_of_e= (int*)alloc((size_t)E * 4);
    int* pe_dst  = (int*)alloc((size_t)E * 4);
    int* boff    = (int*)alloc((size_t)(NREG * NCHUNK + 1) * 4);
    char* zbase   = ws + off;
    int* counts   = (int*)alloc((size_t)N * 4);
    int* cursor   = (int*)alloc((size_t)N * 4);
    float* meanb  = (float*)alloc((size_t)B * 4);
    float* cedge  = (float*)alloc(4);
    size_t zbytes = (size_t)((ws + off) - zbase);
    float* partial = wbuf;   // alias: wbuf dead after k_rep; 32.8 MB <= 41 MB

    hipMemsetAsync(zbase, 0, zbytes, stream);

    k_hist<<<1024, 256, 0, stream>>>(edst, counts);
    k_scan<<<1, 1024, 0, stream>>>(counts, dst_off, N);
    k_roff<<<(NREG + 256) / 256, 256, 0, stream>>>(esrc, roff);
    k_scatter<<<1024, 256, 0, stream>>>(esrc, edst, dst_off, cursor,
                                        csr_src, pos_of_e);
    k_bucket<<<NREG, 256, 0, stream>>>(edst, roff, boff, pe_dst);
    k_mean<<<B * MEAN_BLOCKS_PER_B, 256, 0, stream>>>(eattr, meanb);
    k_cedge<<<1, 64, 0, stream>>>(lin_edge, att_edge, cedge);
    k_gemm<<<(B * N) / 256, 256, 0, stream>>>(x, W, att_src, att_dst,
                                              hu, a_src, a_dst);
    k_edgew<<<E / 256, 256, 0, stream>>>(eattr, esrc, edst, pos_of_e,
                                         a_src, a_dst, cedge, wbuf);
    k_rep<<<N, 256, 0, stream>>>(hu, a_src, a_dst, wbuf, bias, meanb, cedge,
                                 dst_off, csr_src, repu);
    k_pool<<<NREG * NCHUNK, 256, 0, stream>>>(repu, boff, pe_dst, partial);
    k_combine<<<NREG, 256, 0, stream>>>(repu, partial, out);
}